// Round 7
// baseline (616.198 us; speedup 1.0000x reference)
//
#include <hip/hip_runtime.h>
#include <stdint.h>

// Problem constants: B=4, S=2048, D=1024, H=1024, heads=16, d_k=64.
// Pipeline: fused cast->bf16, fused QKV GEMM (MFMA, BK=32 dbuf single-barrier
// prefetch, LDS-bounced epilogues, V transposed per head), flash attention
// (MFMA, no-max exp2 softmax, S^T trick, MFMA row-sums, 256-q tile / 8 waves,
// single-buffer K/V + register prefetch -> 3 blocks/CU), out GEMM (same
// BK=32 dbuf structure, f32 out).

using bf16x8 = __attribute__((ext_vector_type(8))) short;   // 8 bf16 = 4 VGPRs
using f32x4  = __attribute__((ext_vector_type(4))) float;   // MFMA C/D frag

#define QSCALE 0.18033688f  // 1/sqrt(64) * log2(e): scores come out log2-scaled -> exp2

__device__ __forceinline__ unsigned short f2bf(float f) {
    unsigned u = __builtin_bit_cast(unsigned, f);
    u += 0x7fffu + ((u >> 16) & 1u);          // RNE
    return (unsigned short)(u >> 16);
}

// pack two f32 -> two bf16 in one dword: round-to-nearest (ties away) + v_perm
__device__ __forceinline__ unsigned pack2bf(float f0, float f1) {
    unsigned u0 = __builtin_bit_cast(unsigned, f0) + 0x8000u;
    unsigned u1 = __builtin_bit_cast(unsigned, f1) + 0x8000u;
    return __builtin_amdgcn_perm(u1, u0, 0x07060302);  // {hi16(u1),hi16(u0)}
}

// async global->LDS, 16B per lane; LDS dest = wave-uniform base + lane*16
__device__ __forceinline__ void gld16(const void* g, void* l) {
    void* gnc = (void*)g;
    __builtin_amdgcn_global_load_lds((__attribute__((address_space(1))) void*)gnc,
                                     (__attribute__((address_space(3))) void*)l,
                                     16, 0, 0);
}

// swizzled LDS short-offset for (row R, 16B-granule g) in a 64-short-row tile
__device__ __forceinline__ int swz(int R, int g) {
    return R * 64 + ((g ^ (R & 7)) << 3);
}

// ---------------------------------------------------------------- fused casts
__global__ void castall(const float* __restrict__ X, const float* __restrict__ Wq,
                        const float* __restrict__ Wk, const float* __restrict__ Wv,
                        const float* __restrict__ Wo, unsigned short* __restrict__ Xb,
                        unsigned short* __restrict__ Wqkvb, unsigned short* __restrict__ Wob) {
    const int bx = blockIdx.x;
    const float* src; unsigned short* dst; int idx;
    if (bx < 8192) { src = X; dst = Xb; idx = bx * 256 + threadIdx.x; }
    else {
        const int r = bx - 8192, w = r >> 10;
        idx = (r & 1023) * 256 + threadIdx.x;
        src = (w == 0) ? Wq : (w == 1) ? Wk : (w == 2) ? Wv : Wo;
        dst = (w == 3) ? Wob : Wqkvb + (size_t)w * 1048576;
    }
    float4 v = ((const float4*)src)[idx];
    ((uint2*)dst)[idx] = make_uint2(pack2bf(v.x, v.y), pack2bf(v.z, v.w));
}

// ---------------------------------------------------------------- fused QKV GEMM
// A: (8192,1024) bf16. Wqkv: 3 stacked (1024,1024) bf16.
// blockIdx.x: [0,8)=Q, [8,16)=K, [16,24)=V. Q scaled by QSCALE; V stored
// transposed per head: Vt[(b*1024 + n)*2048 + s].
// BK=32 dbuf, ONE barrier per kt: prefetch kt+1 issued right after the
// barrier that publishes kt -> staging latency hidden behind 16 MFMAs.
// 64B rows: b128 frag reads naturally bank-balanced (no swizzle needed).
__global__ __launch_bounds__(256) void gemm_qkv(const unsigned short* __restrict__ A,
                                                const unsigned short* __restrict__ Wqkv,
                                                const float* __restrict__ bq,
                                                const float* __restrict__ bk,
                                                const float* __restrict__ bv,
                                                unsigned short* __restrict__ Qb,
                                                unsigned short* __restrict__ Kb,
                                                unsigned short* __restrict__ Vt) {
    __shared__ alignas(16) unsigned short smem[17408];   // 34816 B
    unsigned short* sA = smem;          // [2][4096] shorts (8KB x2)
    unsigned short* sB = smem + 8192;   // [2][4096]
    unsigned short* OT = smem;          // epilogue 128x136 tile (aliased)

    const int tid  = threadIdx.x;
    const int lane = tid & 63;
    const int wave = tid >> 6;
    const int quad = lane >> 4;
    const int l15  = lane & 15;
    const int srow = lane >> 2;         // 0..15 row within 16-row chunk
    const int scol = (lane & 3) * 8;    // short offset within 64B row
    const int nb   = blockIdx.x >> 3;   // 0=Q 1=K 2=V
    const int col0 = (blockIdx.x & 7) * 128;
    const int row0 = blockIdx.y * 128;
    const unsigned short* W = Wqkv + ((size_t)nb << 20);
    const float* bias = (nb == 0) ? bq : (nb == 1) ? bk : bv;
    const int wm = wave >> 1, wn = wave & 1;

    f32x4 acc[4][4];
#pragma unroll
    for (int i = 0; i < 4; i++)
#pragma unroll
        for (int j = 0; j < 4; j++) acc[i][j] = f32x4{0.f, 0.f, 0.f, 0.f};

#define QKV_STAGE(kt_, buf_)                                                             \
    {                                                                                    \
        _Pragma("unroll")                                                                \
        for (int i = 0; i < 2; i++) {                                                    \
            const int c = wave * 2 + i;                                                  \
            gld16(A + (size_t)(row0 + c * 16 + srow) * 1024 + (kt_) * 32 + scol,         \
                  &sA[(buf_) * 4096 + c * 512]);                                         \
            gld16(W + (size_t)(col0 + c * 16 + srow) * 1024 + (kt_) * 32 + scol,         \
                  &sB[(buf_) * 4096 + c * 512]);                                         \
        }                                                                                \
    }

    QKV_STAGE(0, 0)
    for (int kt = 0; kt < 32; ++kt) {
        const int buf = kt & 1;
        __syncthreads();                       // publishes buf (drains prefetch)
        if (kt < 31) QKV_STAGE(kt + 1, buf ^ 1)
        bf16x8 a[4], b[4];
#pragma unroll
        for (int i = 0; i < 4; i++) {
            a[i] = *(const bf16x8*)&sA[buf * 4096 + (wm * 64 + i * 16 + l15) * 32 + quad * 8];
            b[i] = *(const bf16x8*)&sB[buf * 4096 + (wn * 64 + i * 16 + l15) * 32 + quad * 8];
        }
#pragma unroll
        for (int i = 0; i < 4; i++)
#pragma unroll
            for (int j = 0; j < 4; j++)
                acc[i][j] = __builtin_amdgcn_mfma_f32_16x16x32_bf16(a[i], b[j], acc[i][j], 0, 0, 0);
    }
#undef QKV_STAGE
    __syncthreads();                           // staging dead; OT may alias

    // ---- epilogue phase 1: acc -> LDS out-tile (stride 136 shorts)
    if (nb != 2) {
        const float sc = (nb == 0) ? QSCALE : 1.0f;
#pragma unroll
        for (int i = 0; i < 4; i++) {
#pragma unroll
            for (int j = 0; j < 4; j++) {
                const int ct  = wn * 64 + j * 16 + l15;
                const float bvv = bias[col0 + ct];
                const int rt  = wm * 64 + i * 16 + quad * 4;
#pragma unroll
                for (int r = 0; r < 4; r++)
                    OT[(rt + r) * 136 + ct] = f2bf((acc[i][j][r] + bvv) * sc);
            }
        }
    } else {
#pragma unroll
        for (int i = 0; i < 4; i++) {
#pragma unroll
            for (int j = 0; j < 4; j++) {
                const int ct  = wn * 64 + j * 16 + l15;          // d within tile
                const float bvv = bias[col0 + ct];
                const int rt  = wm * 64 + i * 16 + quad * 4;     // s within tile
                *(uint2*)&OT[ct * 136 + rt] =
                    make_uint2(pack2bf(acc[i][j][0] + bvv, acc[i][j][1] + bvv),
                               pack2bf(acc[i][j][2] + bvv, acc[i][j][3] + bvv));
            }
        }
    }
    __syncthreads();

    // ---- epilogue phase 2: coalesced b128 stores
    const int rr   = wave * 32 + (lane >> 1);
    const int half = lane & 1;
    if (nb != 2) {
        unsigned short* C = (nb == 0) ? Qb : Kb;
        unsigned short* gdst = C + (size_t)(row0 + rr) * 1024 + col0 + half * 64;
#pragma unroll
        for (int k = 0; k < 8; k++)
            *(bf16x8*)(gdst + k * 8) = *(const bf16x8*)&OT[rr * 136 + half * 64 + k * 8];
    } else {
        const int bb = row0 >> 11, s0l = row0 & 2047;
        unsigned short* gdst = Vt + ((size_t)(bb * 1024 + col0 + rr)) * 2048 + s0l + half * 64;
#pragma unroll
        for (int k = 0; k < 8; k++)
            *(bf16x8*)(gdst + k * 8) = *(const bf16x8*)&OT[rr * 136 + half * 64 + k * 8];
    }
}

// ---------------------------------------------------------------- out GEMM (f32 out)
// Same BK=32 dbuf single-barrier structure; direct f32 epilogue.
__global__ __launch_bounds__(256) void gemm_out(const unsigned short* __restrict__ A,
                                                const unsigned short* __restrict__ W,
                                                const float* __restrict__ bias,
                                                float* __restrict__ C) {
    __shared__ alignas(16) unsigned short sA[2][4096];
    __shared__ alignas(16) unsigned short sB[2][4096];
    const int tid  = threadIdx.x;
    const int lane = tid & 63;
    const int wave = tid >> 6;
    const int quad = lane >> 4;
    const int l15  = lane & 15;
    const int srow = lane >> 2;
    const int scol = (lane & 3) * 8;
    const int row0 = blockIdx.y * 128;
    const int col0 = blockIdx.x * 128;
    const int wm = wave >> 1, wn = wave & 1;

    f32x4 acc[4][4];
#pragma unroll
    for (int i = 0; i < 4; i++)
#pragma unroll
        for (int j = 0; j < 4; j++) acc[i][j] = f32x4{0.f, 0.f, 0.f, 0.f};

#define GO_STAGE(kt_, buf_)                                                              \
    {                                                                                    \
        _Pragma("unroll")                                                                \
        for (int i = 0; i < 2; i++) {                                                    \
            const int c = wave * 2 + i;                                                  \
            gld16(A + (size_t)(row0 + c * 16 + srow) * 1024 + (kt_) * 32 + scol,         \
                  &sA[buf_][c * 512]);                                                   \
            gld16(W + (size_t)(col0 + c * 16 + srow) * 1024 + (kt_) * 32 + scol,         \
                  &sB[buf_][c * 512]);                                                   \
        }                                                                                \
    }

    GO_STAGE(0, 0)
    for (int kt = 0; kt < 32; ++kt) {
        const int buf = kt & 1;
        __syncthreads();
        if (kt < 31) GO_STAGE(kt + 1, buf ^ 1)
        bf16x8 a[4], b[4];
#pragma unroll
        for (int i = 0; i < 4; i++) {
            a[i] = *(const bf16x8*)&sA[buf][(wm * 64 + i * 16 + l15) * 32 + quad * 8];
            b[i] = *(const bf16x8*)&sB[buf][(wn * 64 + i * 16 + l15) * 32 + quad * 8];
        }
#pragma unroll
        for (int i = 0; i < 4; i++)
#pragma unroll
            for (int j = 0; j < 4; j++)
                acc[i][j] = __builtin_amdgcn_mfma_f32_16x16x32_bf16(a[i], b[j], acc[i][j], 0, 0, 0);
    }
#undef GO_STAGE

#pragma unroll
    for (int i = 0; i < 4; i++) {
#pragma unroll
        for (int j = 0; j < 4; j++) {
            const int col   = col0 + wn * 64 + j * 16 + l15;
            const float bvv = bias[col];
            const int rbase = row0 + wm * 64 + i * 16 + quad * 4;
#pragma unroll
            for (int r = 0; r < 4; r++)
                C[(size_t)(rbase + r) * 1024 + col] = acc[i][j][r] + bvv;
        }
    }
}

// ---------------------------------------------------------------- flash attention
// Q, K: (B*S, 1024) bf16; Q pre-scaled by QSCALE (fold softmax scale + log2e).
// Vt: (B*1024, 2048) bf16. Ctx out: (B*S, 1024) bf16.
// Block: 256 q-rows of one (b,h), 8 waves; wave owns 32 q-rows; 32 k-tiles.
// SINGLE-buffer K/V + REGISTER prefetch: global->VGPR issued after barrier-1,
// ds_write (waits own vmcnt) at top of next iter, barrier-2 at end of compute
// proves reads done. LDS 52KB -> 3 blocks/CU (24 waves, 3 barrier groups).
__global__ __launch_bounds__(512, 6) void attn(const unsigned short* __restrict__ Q,
                                               const unsigned short* __restrict__ K,
                                               const unsigned short* __restrict__ Vt,
                                               unsigned short* __restrict__ Ctx) {
    __shared__ alignas(16) unsigned short Kl[4096];        // [krow][d], swizzled (8KB)
    __shared__ alignas(16) unsigned short Vl[4096];        // [d][krow], swizzled
    __shared__ alignas(16) unsigned short Pl[8][32][72];   // per-wave P (36.9KB)

    const int tid  = threadIdx.x;
    const int lane = tid & 63;
    const int wave = tid >> 6;        // 0..7
    const int quad = lane >> 4;
    const int l15  = lane & 15;
    const int lr   = lane >> 3;
    const int lcs  = (((lane & 7) ^ lr) << 3);   // swizzled source granule

    const int qt = blockIdx.x, h = blockIdx.y, b = blockIdx.z;
    const int q0 = qt * 256;
    const size_t tokbase = (size_t)b * 2048;

    // staging source pointers (wave stages rows wave*8+lr of each 64x64 tile)
    const int rr = wave * 8 + lr;
    const unsigned short* Kg = K + (tokbase + rr) * 1024 + h * 64 + lcs;
    const unsigned short* Vg = Vt + ((size_t)(b * 1024 + h * 64 + rr)) * 2048 + lcs;

    bf16x8 qa[2][2];
#pragma unroll
    for (int mt = 0; mt < 2; ++mt)
#pragma unroll
        for (int kx = 0; kx < 2; ++kx)
            qa[mt][kx] = *(const bf16x8*)(Q + (tokbase + q0 + wave * 32 + mt * 16 + l15) * 1024 +
                                          h * 64 + kx * 32 + quad * 8);

    f32x4 O[2][4], Osum[2];
#pragma unroll
    for (int mt = 0; mt < 2; ++mt) {
#pragma unroll
        for (int nt = 0; nt < 4; ++nt) O[mt][nt] = f32x4{0.f, 0.f, 0.f, 0.f};
        Osum[mt] = f32x4{0.f, 0.f, 0.f, 0.f};
    }
    const bf16x8 vones = {16256, 16256, 16256, 16256, 16256, 16256, 16256, 16256};  // bf16 1.0

    uint4 kpf, vpf;
    kpf = *(const uint4*)(Kg);                 // tile 0 (K advances 64 rows/tile)
    vpf = *(const uint4*)(Vg);                 // tile 0 (Vt advances 64 cols/tile)

    for (int kt = 0; kt < 32; ++kt) {
        // publish staged regs (auto-waits own vmcnt); lane offset = lane*16B
        *(uint4*)&Kl[wave * 512 + lane * 8] = kpf;
        *(uint4*)&Vl[wave * 512 + lane * 8] = vpf;
        __syncthreads();                       // writes visible to all waves
        if (kt < 31) {                         // prefetch next tile into regs
            kpf = *(const uint4*)(Kg + (size_t)(kt + 1) * 65536);
            vpf = *(const uint4*)(Vg + (kt + 1) * 64);
        }

        // S^T = K @ Q^T  (C layout: row=quad*4+r is K-COL, col=lane&15 is Q-ROW)
        f32x4 St[4][2];
#pragma unroll
        for (int nt = 0; nt < 4; ++nt)
#pragma unroll
            for (int mt = 0; mt < 2; ++mt) St[nt][mt] = f32x4{0.f, 0.f, 0.f, 0.f};
#pragma unroll
        for (int kx = 0; kx < 2; ++kx) {
            bf16x8 kb[4];
#pragma unroll
            for (int nt = 0; nt < 4; ++nt)
                kb[nt] = *(const bf16x8*)&Kl[swz(nt * 16 + l15, kx * 4 + quad)];
#pragma unroll
            for (int nt = 0; nt < 4; ++nt)
#pragma unroll
                for (int mt = 0; mt < 2; ++mt)
                    St[nt][mt] = __builtin_amdgcn_mfma_f32_16x16x32_bf16(kb[nt], qa[mt][kx], St[nt][mt], 0, 0, 0);
        }

        // raw v_exp_f32 (scores pre-scaled by log2e) + perm-pack -> b64 write
#pragma unroll
        for (int mt = 0; mt < 2; ++mt) {
#pragma unroll
            for (int nt = 0; nt < 4; ++nt) {
                float p0 = __builtin_amdgcn_exp2f(St[nt][mt][0]);
                float p1 = __builtin_amdgcn_exp2f(St[nt][mt][1]);
                float p2 = __builtin_amdgcn_exp2f(St[nt][mt][2]);
                float p3 = __builtin_amdgcn_exp2f(St[nt][mt][3]);
                *(uint2*)&Pl[wave][mt * 16 + l15][nt * 16 + quad * 4] =
                    make_uint2(pack2bf(p0, p1), pack2bf(p2, p3));
            }
        }

        // O += P @ V ; Osum += P @ ones  (row-sums on the MFMA pipe)
#pragma unroll
        for (int kx = 0; kx < 2; ++kx) {
            bf16x8 pa[2], vb[4];
#pragma unroll
            for (int mt = 0; mt < 2; ++mt)
                pa[mt] = *(const bf16x8*)&Pl[wave][mt * 16 + l15][kx * 32 + quad * 8];
#pragma unroll
            for (int nt = 0; nt < 4; ++nt)
                vb[nt] = *(const bf16x8*)&Vl[swz(nt * 16 + l15, kx * 4 + quad)];
#pragma unroll
            for (int mt = 0; mt < 2; ++mt) {
#pragma unroll
                for (int nt = 0; nt < 4; ++nt)
                    O[mt][nt] = __builtin_amdgcn_mfma_f32_16x16x32_bf16(pa[mt], vb[nt], O[mt][nt], 0, 0, 0);
                Osum[mt] = __builtin_amdgcn_mfma_f32_16x16x32_bf16(pa[mt], vones, Osum[mt], 0, 0, 0);
            }
        }
        __syncthreads();                       // all reads of Kl/Vl done
    }

    // normalize + store ctx; O C-layout rows = quad*4+r match Osum rows exactly
#pragma unroll
    for (int mt = 0; mt < 2; ++mt) {
#pragma unroll
        for (int r = 0; r < 4; ++r) {
            const float inv = 1.0f / Osum[mt][r];
            const int row   = q0 + wave * 32 + mt * 16 + quad * 4 + r;
            const size_t base = (tokbase + row) * 1024 + h * 64;
#pragma unroll
            for (int nt = 0; nt < 4; ++nt)
                Ctx[base + nt * 16 + l15] = f2bf(O[mt][nt][r] * inv);
        }
    }
}

// ---------------------------------------------------------------- launch
extern "C" void kernel_launch(void* const* d_in, const int* in_sizes, int n_in,
                              void* d_out, int out_size, void* d_ws, size_t ws_size,
                              hipStream_t stream) {
    (void)in_sizes; (void)n_in; (void)out_size; (void)ws_size;
    const float* X  = (const float*)d_in[0];
    const float* Wq = (const float*)d_in[1];
    const float* bq = (const float*)d_in[2];
    const float* Wk = (const float*)d_in[3];
    const float* bk = (const float*)d_in[4];
    const float* Wv = (const float*)d_in[5];
    const float* bv = (const float*)d_in[6];
    const float* Wo = (const float*)d_in[7];
    const float* bo = (const float*)d_in[8];

    char* ws = (char*)d_ws;
    unsigned short* Xb    = (unsigned short*)(ws);                        // 16 MB (aliased as Ctx)
    unsigned short* Qb    = (unsigned short*)(ws + (size_t)16 * 1048576); // 16 MB
    unsigned short* Kb    = (unsigned short*)(ws + (size_t)32 * 1048576); // 16 MB
    unsigned short* Vt    = (unsigned short*)(ws + (size_t)48 * 1048576); // 16 MB
    unsigned short* Wqkvb = (unsigned short*)(ws + (size_t)64 * 1048576); // 6 MB
    unsigned short* Wob   = (unsigned short*)(ws + (size_t)70 * 1048576); // 2 MB
    unsigned short* Ctx   = Xb;  // X dead after QKV GEMM (stream-ordered)

    castall<<<dim3(12288), 256, 0, stream>>>(X, Wq, Wk, Wv, Wo, Xb, Wqkvb, Wob);
    gemm_qkv<<<dim3(24, 64), 256, 0, stream>>>(Xb, Wqkvb, bq, bk, bv, Qb, Kb, Vt);
    attn<<<dim3(8, 16, 4), 512, 0, stream>>>(Qb, Kb, Vt, Ctx);
    gemm_out<<<dim3(8, 64), 256, 0, stream>>>(Ctx, Wob, bo, (float*)d_out);
}